// Round 1
// baseline (4148.912 us; speedup 1.0000x reference)
//
#include <hip/hip_runtime.h>

#define L_SEQ 4680
#define DIMSZ 1536
#define NHEAD 12
#define HDIM 128
#define FRAME 1560  // H*W = 30*52
#define SCALE 0.08838834764831845f  // 1/sqrt(128)

// ---------------- GEMM: C[M][N] = A[M][K] * W[N][K]^T + bias, K=N=1536 ----------------
__global__ __launch_bounds__(256) void gemm_bias(
    const float* __restrict__ A, const float* __restrict__ W,
    const float* __restrict__ bias, float* __restrict__ C, int M) {
  const int K = DIMSZ, N = DIMSZ;
  __shared__ float As[32][76];
  __shared__ float Ws[32][76];
  const int m0 = blockIdx.x * 64;
  const int n0 = blockIdx.y * 64;
  const int t = threadIdx.x;
  const int ty = t >> 4, tx = t & 15;
  float acc[4][4] = {};
  for (int k0 = 0; k0 < K; k0 += 32) {
#pragma unroll
    for (int pass = 0; pass < 2; ++pass) {
      int idx = pass * 256 + t;
      int r = idx >> 3, c4 = idx & 7;
      float4 av = make_float4(0.f, 0.f, 0.f, 0.f);
      int gr = m0 + r;
      if (gr < M) av = *(const float4*)&A[(size_t)gr * K + k0 + c4 * 4];
      As[c4 * 4 + 0][r] = av.x; As[c4 * 4 + 1][r] = av.y;
      As[c4 * 4 + 2][r] = av.z; As[c4 * 4 + 3][r] = av.w;
      float4 wv = *(const float4*)&W[(size_t)(n0 + r) * K + k0 + c4 * 4];
      Ws[c4 * 4 + 0][r] = wv.x; Ws[c4 * 4 + 1][r] = wv.y;
      Ws[c4 * 4 + 2][r] = wv.z; Ws[c4 * 4 + 3][r] = wv.w;
    }
    __syncthreads();
#pragma unroll
    for (int kk = 0; kk < 32; ++kk) {
      float a[4], w[4];
      *(float4*)a = *(const float4*)&As[kk][ty * 4];
      *(float4*)w = *(const float4*)&Ws[kk][tx * 4];
#pragma unroll
      for (int i = 0; i < 4; ++i)
#pragma unroll
        for (int j = 0; j < 4; ++j)
          acc[i][j] += a[i] * w[j];
    }
    __syncthreads();
  }
  float b4[4];
  *(float4*)b4 = *(const float4*)&bias[n0 + tx * 4];
#pragma unroll
  for (int i = 0; i < 4; ++i) {
    int row = m0 + ty * 4 + i;
    if (row < M) {
      float o[4];
#pragma unroll
      for (int j = 0; j < 4; ++j) o[j] = acc[i][j] + b4[j];
      *(float4*)&C[(size_t)row * N + n0 + tx * 4] = *(float4*)o;
    }
  }
}

// ------------- fused RMSNorm(row of 1536) + RoPE, in-place on q (y=0) / k (y=1) -------------
__global__ __launch_bounds__(256) void norm_rope(
    float* __restrict__ q, float* __restrict__ k,
    const float* __restrict__ gq, const float* __restrict__ gk,
    const float* __restrict__ freqs) {
  const int pos = blockIdx.x;
  float* row = (blockIdx.y == 0 ? q : k) + (size_t)pos * DIMSZ;
  const float* g = blockIdx.y == 0 ? gq : gk;
  const int t = threadIdx.x;
  float2 ab[3];
  float ss = 0.f;
#pragma unroll
  for (int i = 0; i < 3; ++i) {
    ab[i] = *(const float2*)&row[2 * (t + 256 * i)];
    ss += ab[i].x * ab[i].x + ab[i].y * ab[i].y;
  }
#pragma unroll
  for (int m = 32; m; m >>= 1) ss += __shfl_xor(ss, m);
  __shared__ float part[4];
  if ((t & 63) == 0) part[t >> 6] = ss;
  __syncthreads();
  const float tot = part[0] + part[1] + part[2] + part[3];
  const float scale = rsqrtf(tot * (1.f / DIMSZ) + 1e-6f);
  const int f = pos / FRAME;
  const int rem = pos - f * FRAME;
  const int hh = rem / 52;
  const int ww = rem - hh * 52;
#pragma unroll
  for (int i = 0; i < 3; ++i) {
    const int p = t + 256 * i;     // pair index 0..767 within row
    const int c = p & 63;          // pair index within head
    const int pr = c < 22 ? f : (c < 43 ? hh : ww);
    const float cs = freqs[(pr * 64 + c) * 2 + 0];
    const float sn = freqs[(pr * 64 + c) * 2 + 1];
    const float a = ab[i].x * scale * g[2 * p];
    const float b = ab[i].y * scale * g[2 * p + 1];
    float2 o;
    o.x = a * cs - b * sn;
    o.y = a * sn + b * cs;
    *(float2*)&row[2 * p] = o;
  }
}

// ---------------- prefix flash attention, fp32, 64-row Q tiles ----------------
__global__ __launch_bounds__(256) void attn_kernel(
    const float* __restrict__ q, const float* __restrict__ k,
    const float* __restrict__ v, float* __restrict__ ao) {
  __shared__ float Qt[128][76];  // [d][row]
  __shared__ float Kt[128][76];  // [d][key]
  __shared__ float Vs[64][132];  // [key][d]
  __shared__ float Ss[64][68];   // scores / p
  __shared__ float mrow[64], lrow[64], frow[64], red[64][4];
  const int q0 = blockIdx.x * 64;
  const int h = blockIdx.y;
  const int t = threadIdx.x;
  const int ty = t >> 4, tx = t & 15;

#pragma unroll
  for (int pass = 0; pass < 8; ++pass) {
    int idx = pass * 256 + t;
    int r = idx >> 5, d4 = idx & 31;
    float4 val = make_float4(0.f, 0.f, 0.f, 0.f);
    int gr = q0 + r;
    if (gr < L_SEQ) val = *(const float4*)&q[(size_t)gr * DIMSZ + h * HDIM + d4 * 4];
    Qt[d4 * 4 + 0][r] = val.x; Qt[d4 * 4 + 1][r] = val.y;
    Qt[d4 * 4 + 2][r] = val.z; Qt[d4 * 4 + 3][r] = val.w;
  }
  if (t < 64) { mrow[t] = -1e30f; lrow[t] = 0.f; }
  float acc[4][8] = {};
  const int fmax = min(q0 + 63, L_SEQ - 1) / FRAME;
  const int kend = (fmax + 1) * FRAME;  // prefix mask: max klim over tile rows
  __syncthreads();

  for (int k0 = 0; k0 < kend; k0 += 64) {
    // stage K (transposed) and V tiles
#pragma unroll
    for (int pass = 0; pass < 8; ++pass) {
      int idx = pass * 256 + t;
      int c = idx >> 5, d4 = idx & 31;
      int gc = k0 + c;
      float4 kv = make_float4(0.f, 0.f, 0.f, 0.f);
      float4 vv = make_float4(0.f, 0.f, 0.f, 0.f);
      if (gc < L_SEQ) {
        kv = *(const float4*)&k[(size_t)gc * DIMSZ + h * HDIM + d4 * 4];
        vv = *(const float4*)&v[(size_t)gc * DIMSZ + h * HDIM + d4 * 4];
      }
      Kt[d4 * 4 + 0][c] = kv.x; Kt[d4 * 4 + 1][c] = kv.y;
      Kt[d4 * 4 + 2][c] = kv.z; Kt[d4 * 4 + 3][c] = kv.w;
      *(float4*)&Vs[c][d4 * 4] = vv;
    }
    __syncthreads();

    // S = Q K^T (each thread 4x4)
    float s[4][4] = {};
#pragma unroll 4
    for (int d = 0; d < 128; ++d) {
      float a[4], b[4];
      *(float4*)a = *(const float4*)&Qt[d][ty * 4];
      *(float4*)b = *(const float4*)&Kt[d][tx * 4];
#pragma unroll
      for (int i = 0; i < 4; ++i)
#pragma unroll
        for (int j = 0; j < 4; ++j)
          s[i][j] += a[i] * b[j];
    }
    // scale + prefix mask
#pragma unroll
    for (int i = 0; i < 4; ++i) {
      const int gr = min(q0 + ty * 4 + i, L_SEQ - 1);
      const int klim = (gr / FRAME + 1) * FRAME;
#pragma unroll
      for (int j = 0; j < 4; ++j) {
        const int gc = k0 + tx * 4 + j;
        float sv = s[i][j] * SCALE;
        if (gc >= klim) sv = -1e30f;
        s[i][j] = sv;
        Ss[ty * 4 + i][tx * 4 + j] = sv;
      }
    }
    __syncthreads();
    // row max (4 partials per row)
    {
      int r = t >> 2, pc = (t & 3) * 16;
      float mx = -1e30f;
      for (int j = 0; j < 16; ++j) mx = fmaxf(mx, Ss[r][pc + j]);
      red[r][t & 3] = mx;
    }
    __syncthreads();
    if (t < 64) {
      float mx = fmaxf(fmaxf(red[t][0], red[t][1]), fmaxf(red[t][2], red[t][3]));
      float mo = mrow[t];
      float mn = fmaxf(mo, mx);
      frow[t] = __expf(mo - mn);
      mrow[t] = mn;
    }
    __syncthreads();
    // p = exp(s-m); rescale acc
#pragma unroll
    for (int i = 0; i < 4; ++i) {
      const float m = mrow[ty * 4 + i];
      const float fr = frow[ty * 4 + i];
#pragma unroll
      for (int j = 0; j < 8; ++j) acc[i][j] *= fr;
#pragma unroll
      for (int j = 0; j < 4; ++j)
        Ss[ty * 4 + i][tx * 4 + j] = __expf(s[i][j] - m);
    }
    __syncthreads();
    // row sums
    {
      int r = t >> 2, pc = (t & 3) * 16;
      float sm = 0.f;
      for (int j = 0; j < 16; ++j) sm += Ss[r][pc + j];
      red[r][t & 3] = sm;
    }
    __syncthreads();
    if (t < 64)
      lrow[t] = lrow[t] * frow[t] + (red[t][0] + red[t][1] + red[t][2] + red[t][3]);
    // PV: acc[i][j] over dims tx*8..tx*8+7
#pragma unroll 2
    for (int c = 0; c < 64; ++c) {
      float pv[4];
#pragma unroll
      for (int i = 0; i < 4; ++i) pv[i] = Ss[ty * 4 + i][c];
      float vv[8];
      *(float4*)vv = *(const float4*)&Vs[c][tx * 8];
      *(float4*)(vv + 4) = *(const float4*)&Vs[c][tx * 8 + 4];
#pragma unroll
      for (int i = 0; i < 4; ++i)
#pragma unroll
        for (int j = 0; j < 8; ++j)
          acc[i][j] += pv[i] * vv[j];
    }
    __syncthreads();
  }
#pragma unroll
  for (int i = 0; i < 4; ++i) {
    int gr = q0 + ty * 4 + i;
    if (gr < L_SEQ) {
      float inv = 1.f / lrow[ty * 4 + i];
      float o[8];
#pragma unroll
      for (int j = 0; j < 8; ++j) o[j] = acc[i][j] * inv;
      *(float4*)&ao[(size_t)gr * DIMSZ + h * HDIM + tx * 8] = *(float4*)o;
      *(float4*)&ao[(size_t)gr * DIMSZ + h * HDIM + tx * 8 + 4] = *(float4*)(o + 4);
    }
  }
}

extern "C" void kernel_launch(void* const* d_in, const int* in_sizes, int n_in,
                              void* d_out, int out_size, void* d_ws, size_t ws_size,
                              hipStream_t stream) {
  const float* x  = (const float*)d_in[0];
  const float* wq = (const float*)d_in[1];
  const float* bq = (const float*)d_in[2];
  const float* wk = (const float*)d_in[3];
  const float* bk = (const float*)d_in[4];
  const float* wv = (const float*)d_in[5];
  const float* bv = (const float*)d_in[6];
  const float* wo = (const float*)d_in[7];
  const float* bo = (const float*)d_in[8];
  const float* gq = (const float*)d_in[9];
  const float* gk = (const float*)d_in[10];
  const float* freqs = (const float*)d_in[11];
  float* out = (float*)d_out;
  float* ws = (float*)d_ws;
  const size_t LD = (size_t)L_SEQ * DIMSZ;
  float* q  = ws;
  float* k  = ws + LD;
  float* v  = ws + 2 * LD;
  float* ao = ws + 3 * LD;

  dim3 blk(256);
  dim3 gemm_grid((L_SEQ + 63) / 64, DIMSZ / 64);
  gemm_bias<<<gemm_grid, blk, 0, stream>>>(x, wq, bq, q, L_SEQ);
  gemm_bias<<<gemm_grid, blk, 0, stream>>>(x, wk, bk, k, L_SEQ);
  gemm_bias<<<gemm_grid, blk, 0, stream>>>(x, wv, bv, v, L_SEQ);
  norm_rope<<<dim3(L_SEQ, 2), blk, 0, stream>>>(q, k, gq, gk, freqs);
  attn_kernel<<<dim3((L_SEQ + 63) / 64, NHEAD), blk, 0, stream>>>(q, k, v, ao);
  gemm_bias<<<gemm_grid, blk, 0, stream>>>(ao, wo, bo, out, L_SEQ);
}

// Round 2
// 1616.695 us; speedup vs baseline: 2.5663x; 2.5663x over previous
//
#include <hip/hip_runtime.h>

#define L_SEQ 4680
#define DIMSZ 1536
#define NHEAD 12
#define HDIM 128
#define FRAME 1560
#define SCALE 0.08838834764831845f  // 1/sqrt(128)

typedef float f32x4 __attribute__((ext_vector_type(4)));
typedef short s16x8 __attribute__((ext_vector_type(8)));
typedef _Float16 f16;
typedef _Float16 f16x8 __attribute__((ext_vector_type(8)));

__device__ __forceinline__ unsigned short f2bf(float f) {
  unsigned u = __float_as_uint(f);
  unsigned r = u + 0x7fffu + ((u >> 16) & 1u);
  return (unsigned short)(r >> 16);
}
__device__ __forceinline__ float bf2f(unsigned short h) {
  return __uint_as_float(((unsigned)h) << 16);
}

// ============ GEMM: C[M][1536] = A[M][1536] * W[1536][1536]^T + bias ============
// bf16 hi/lo split, 3-pass MFMA. 128x128 tile, BK=64, 4 waves (2x2).
__global__ __launch_bounds__(256) void gemm_mfma(
    const float* __restrict__ A, const float* __restrict__ Wt,
    const float* __restrict__ bias, float* __restrict__ C, int M) {
  __shared__ unsigned short Ah[128 * 64];
  __shared__ unsigned short Al[128 * 64];
  __shared__ unsigned short Bh[128 * 64];
  __shared__ unsigned short Bl[128 * 64];
  const int t = threadIdx.x;
  const int lane = t & 63, w = t >> 6;
  const int g = lane >> 4, ln = lane & 15;
  const int wm = w >> 1, wn = w & 1;
  const int bm0 = blockIdx.x * 128, bn0 = blockIdx.y * 128;
  f32x4 acc[4][4] = {};

  for (int k0 = 0; k0 < DIMSZ; k0 += 64) {
    __syncthreads();
#pragma unroll
    for (int pass = 0; pass < 4; ++pass) {
      int ch = t + 256 * pass;           // 1024 chunks: row 0..127, slot s 0..7 (8 halves)
      int row = ch >> 3, s = ch & 7;
      int off = row * 64 + ((s * 8) ^ ((row & 7) * 8));
      {
        int gr = min(bm0 + row, M - 1);
        const float* src = &A[(size_t)gr * DIMSZ + k0 + s * 8];
        float4 v0 = *(const float4*)src, v1 = *(const float4*)(src + 4);
        float f[8] = {v0.x, v0.y, v0.z, v0.w, v1.x, v1.y, v1.z, v1.w};
        union { unsigned short h[8]; float4 q; } uh, ul;
#pragma unroll
        for (int i = 0; i < 8; ++i) {
          unsigned short hb = f2bf(f[i]);
          uh.h[i] = hb;
          ul.h[i] = f2bf(f[i] - bf2f(hb));
        }
        *(float4*)&Ah[off] = uh.q;
        *(float4*)&Al[off] = ul.q;
      }
      {
        int gr = bn0 + row;  // N=1536 divisible by 128
        const float* src = &Wt[(size_t)gr * DIMSZ + k0 + s * 8];
        float4 v0 = *(const float4*)src, v1 = *(const float4*)(src + 4);
        float f[8] = {v0.x, v0.y, v0.z, v0.w, v1.x, v1.y, v1.z, v1.w};
        union { unsigned short h[8]; float4 q; } uh, ul;
#pragma unroll
        for (int i = 0; i < 8; ++i) {
          unsigned short hb = f2bf(f[i]);
          uh.h[i] = hb;
          ul.h[i] = f2bf(f[i] - bf2f(hb));
        }
        *(float4*)&Bh[off] = uh.q;
        *(float4*)&Bl[off] = ul.q;
      }
    }
    __syncthreads();
#pragma unroll
    for (int kc = 0; kc < 2; ++kc) {
      s16x8 ah[4], al[4], bh[4], bl[4];
#pragma unroll
      for (int mi = 0; mi < 4; ++mi) {
        int row = wm * 64 + mi * 16 + ln;
        int off = row * 64 + ((g * 8 + kc * 32) ^ ((row & 7) * 8));
        ah[mi] = *(const s16x8*)&Ah[off];
        al[mi] = *(const s16x8*)&Al[off];
      }
#pragma unroll
      for (int ni = 0; ni < 4; ++ni) {
        int row = wn * 64 + ni * 16 + ln;
        int off = row * 64 + ((g * 8 + kc * 32) ^ ((row & 7) * 8));
        bh[ni] = *(const s16x8*)&Bh[off];
        bl[ni] = *(const s16x8*)&Bl[off];
      }
#pragma unroll
      for (int mi = 0; mi < 4; ++mi)
#pragma unroll
        for (int ni = 0; ni < 4; ++ni) {
          acc[mi][ni] = __builtin_amdgcn_mfma_f32_16x16x32_bf16(ah[mi], bh[ni], acc[mi][ni], 0, 0, 0);
          acc[mi][ni] = __builtin_amdgcn_mfma_f32_16x16x32_bf16(ah[mi], bl[ni], acc[mi][ni], 0, 0, 0);
          acc[mi][ni] = __builtin_amdgcn_mfma_f32_16x16x32_bf16(al[mi], bh[ni], acc[mi][ni], 0, 0, 0);
        }
    }
  }
#pragma unroll
  for (int mi = 0; mi < 4; ++mi)
#pragma unroll
    for (int ni = 0; ni < 4; ++ni) {
      int col = bn0 + wn * 64 + ni * 16 + ln;
      float bv = bias[col];
#pragma unroll
      for (int r = 0; r < 4; ++r) {
        int row = bm0 + wm * 64 + mi * 16 + 4 * g + r;
        if (row < M) C[(size_t)row * DIMSZ + col] = acc[mi][ni][r] + bv;
      }
    }
}

// ------------- fused RMSNorm + RoPE, in-place on q (y=0) / k (y=1) -------------
__global__ __launch_bounds__(256) void norm_rope(
    float* __restrict__ q, float* __restrict__ k,
    const float* __restrict__ gq, const float* __restrict__ gk,
    const float* __restrict__ freqs) {
  const int pos = blockIdx.x;
  float* row = (blockIdx.y == 0 ? q : k) + (size_t)pos * DIMSZ;
  const float* g = blockIdx.y == 0 ? gq : gk;
  const int t = threadIdx.x;
  float2 ab[3];
  float ss = 0.f;
#pragma unroll
  for (int i = 0; i < 3; ++i) {
    ab[i] = *(const float2*)&row[2 * (t + 256 * i)];
    ss += ab[i].x * ab[i].x + ab[i].y * ab[i].y;
  }
#pragma unroll
  for (int m = 32; m; m >>= 1) ss += __shfl_xor(ss, m);
  __shared__ float part[4];
  if ((t & 63) == 0) part[t >> 6] = ss;
  __syncthreads();
  const float tot = part[0] + part[1] + part[2] + part[3];
  const float scale = rsqrtf(tot * (1.f / DIMSZ) + 1e-6f);
  const int f = pos / FRAME;
  const int rem = pos - f * FRAME;
  const int hh = rem / 52;
  const int ww = rem - hh * 52;
#pragma unroll
  for (int i = 0; i < 3; ++i) {
    const int p = t + 256 * i;
    const int c = p & 63;
    const int pr = c < 22 ? f : (c < 43 ? hh : ww);
    const float cs = freqs[(pr * 64 + c) * 2 + 0];
    const float sn = freqs[(pr * 64 + c) * 2 + 1];
    const float a = ab[i].x * scale * g[2 * p];
    const float b = ab[i].y * scale * g[2 * p + 1];
    float2 o;
    o.x = a * cs - b * sn;
    o.y = a * sn + b * cs;
    *(float2*)&row[2 * p] = o;
  }
}

// ============ flash attention, fp16 MFMA: 128-row Q tile, 64-key tiles ============
__global__ __launch_bounds__(256) void attn_mfma(
    const float* __restrict__ q, const float* __restrict__ k,
    const float* __restrict__ v, float* __restrict__ ao) {
  __shared__ f16 Qs[128 * 128];   // row-major, XOR-swizzled, 32KB
  __shared__ f16 Ks[64 * 128];    // 16KB
  __shared__ f16 Vt[128 * 64];    // [d][kk], 16KB
  __shared__ f16 Ps[4 * 32 * 64]; // per-wave P, 16KB
  const int q0 = blockIdx.x * 128;
  const int h = blockIdx.y;
  const int t = threadIdx.x;
  const int lane = t & 63, w = t >> 6;
  const int g = lane >> 4, ln = lane & 15;

  // stage Q tile as fp16
#pragma unroll
  for (int pass = 0; pass < 8; ++pass) {
    int ch = t + 256 * pass;        // 2048 chunks: row 0..127, slot 0..15
    int row = ch >> 4, s = ch & 15;
    int gr = min(q0 + row, L_SEQ - 1);
    const float* src = &q[(size_t)gr * DIMSZ + h * HDIM + s * 8];
    float4 v0 = *(const float4*)src, v1 = *(const float4*)(src + 4);
    union { f16 hh[8]; float4 f; } u;
    u.hh[0] = (f16)v0.x; u.hh[1] = (f16)v0.y; u.hh[2] = (f16)v0.z; u.hh[3] = (f16)v0.w;
    u.hh[4] = (f16)v1.x; u.hh[5] = (f16)v1.y; u.hh[6] = (f16)v1.z; u.hh[7] = (f16)v1.w;
    *(float4*)&Qs[row * 128 + ((s * 8) ^ ((row & 7) * 8))] = u.f;
  }

  float m_run[2][4], l_run[2][4];
  f32x4 acc_o[2][8] = {};
  int klim[2][4];
#pragma unroll
  for (int mi = 0; mi < 2; ++mi)
#pragma unroll
    for (int r = 0; r < 4; ++r) {
      m_run[mi][r] = -1e30f;
      l_run[mi][r] = 0.f;
      int gr = min(q0 + w * 32 + mi * 16 + 4 * g + r, L_SEQ - 1);
      klim[mi][r] = (gr / FRAME + 1) * FRAME;
    }
  const int rmax = min(q0 + 127, L_SEQ - 1);
  const int kend = (rmax / FRAME + 1) * FRAME;

  for (int k0 = 0; k0 < kend; k0 += 64) {
    __syncthreads();
    // stage K tile
#pragma unroll
    for (int pass = 0; pass < 4; ++pass) {
      int ch = t + 256 * pass;
      int row = ch >> 4, s = ch & 15;
      int gc = min(k0 + row, L_SEQ - 1);
      const float* src = &k[(size_t)gc * DIMSZ + h * HDIM + s * 8];
      float4 v0 = *(const float4*)src, v1 = *(const float4*)(src + 4);
      union { f16 hh[8]; float4 f; } u;
      u.hh[0] = (f16)v0.x; u.hh[1] = (f16)v0.y; u.hh[2] = (f16)v0.z; u.hh[3] = (f16)v0.w;
      u.hh[4] = (f16)v1.x; u.hh[5] = (f16)v1.y; u.hh[6] = (f16)v1.z; u.hh[7] = (f16)v1.w;
      *(float4*)&Ks[row * 128 + ((s * 8) ^ ((row & 7) * 8))] = u.f;
    }
    // stage V transposed
#pragma unroll
    for (int pass = 0; pass < 8; ++pass) {
      int kk = t & 63;
      int db = (t >> 6) * 4 + pass * 16;
      int gc = min(k0 + kk, L_SEQ - 1);
      float4 vv = *(const float4*)&v[(size_t)gc * DIMSZ + h * HDIM + db];
      float f[4] = {vv.x, vv.y, vv.z, vv.w};
#pragma unroll
      for (int i = 0; i < 4; ++i) {
        int d = db + i;
        Vt[d * 64 + (kk ^ ((d & 7) * 8))] = (f16)f[i];
      }
    }
    __syncthreads();

#pragma unroll
    for (int mi = 0; mi < 2; ++mi) {
      // S strip = Q[w*32+mi*16 .. +16) x K^T (64 keys)
      f32x4 s[4] = {};
      f16x8 qa[4];
#pragma unroll
      for (int kc = 0; kc < 4; ++kc) {
        int row = w * 32 + mi * 16 + ln;
        qa[kc] = *(const f16x8*)&Qs[row * 128 + ((g * 8 + kc * 32) ^ ((row & 7) * 8))];
      }
#pragma unroll
      for (int nb = 0; nb < 4; ++nb)
#pragma unroll
        for (int kc = 0; kc < 4; ++kc) {
          int row = nb * 16 + ln;
          f16x8 kb = *(const f16x8*)&Ks[row * 128 + ((g * 8 + kc * 32) ^ ((row & 7) * 8))];
          s[nb] = __builtin_amdgcn_mfma_f32_16x16x32_f16(qa[kc], kb, s[nb], 0, 0, 0);
        }
      // mask + scale + online softmax
      float p[4][4], rowmax[4];
#pragma unroll
      for (int r = 0; r < 4; ++r) rowmax[r] = -1e30f;
#pragma unroll
      for (int nb = 0; nb < 4; ++nb) {
        int gc = k0 + nb * 16 + ln;
#pragma unroll
        for (int r = 0; r < 4; ++r) {
          float val = s[nb][r] * SCALE;
          if (gc >= klim[mi][r]) val = -1e30f;
          p[nb][r] = val;
          rowmax[r] = fmaxf(rowmax[r], val);
        }
      }
#pragma unroll
      for (int msk = 1; msk < 16; msk <<= 1)
#pragma unroll
        for (int r = 0; r < 4; ++r) rowmax[r] = fmaxf(rowmax[r], __shfl_xor(rowmax[r], msk));
      float fs[4], rsum[4];
#pragma unroll
      for (int r = 0; r < 4; ++r) {
        float mn = fmaxf(m_run[mi][r], rowmax[r]);
        fs[r] = __expf(m_run[mi][r] - mn);
        m_run[mi][r] = mn;
        float sm = 0.f;
#pragma unroll
        for (int nb = 0; nb < 4; ++nb) {
          float e = __expf(p[nb][r] - mn);
          p[nb][r] = e;
          sm += e;
        }
        rsum[r] = sm;
      }
#pragma unroll
      for (int msk = 1; msk < 16; msk <<= 1)
#pragma unroll
        for (int r = 0; r < 4; ++r) rsum[r] += __shfl_xor(rsum[r], msk);
#pragma unroll
      for (int r = 0; r < 4; ++r) l_run[mi][r] = l_run[mi][r] * fs[r] + rsum[r];
#pragma unroll
      for (int db = 0; db < 8; ++db)
#pragma unroll
        for (int r = 0; r < 4; ++r) acc_o[mi][db][r] *= fs[r];
      // write P (fp16) to per-wave LDS
#pragma unroll
      for (int nb = 0; nb < 4; ++nb)
#pragma unroll
        for (int r = 0; r < 4; ++r) {
          int row = mi * 16 + 4 * g + r;
          Ps[w * 2048 + row * 64 + ((nb * 16 + ln) ^ ((row & 7) * 8))] = (f16)p[nb][r];
        }
      // PV
      f16x8 pa[2];
#pragma unroll
      for (int kc = 0; kc < 2; ++kc) {
        int row = mi * 16 + ln;
        pa[kc] = *(const f16x8*)&Ps[w * 2048 + row * 64 + ((kc * 32 + g * 8) ^ ((row & 7) * 8))];
      }
#pragma unroll
      for (int db = 0; db < 8; ++db) {
        int d = db * 16 + ln;
#pragma unroll
        for (int kc = 0; kc < 2; ++kc) {
          f16x8 vb = *(const f16x8*)&Vt[d * 64 + ((kc * 32 + g * 8) ^ ((d & 7) * 8))];
          acc_o[mi][db] = __builtin_amdgcn_mfma_f32_16x16x32_f16(pa[kc], vb, acc_o[mi][db], 0, 0, 0);
        }
      }
    }
  }
  // epilogue
#pragma unroll
  for (int mi = 0; mi < 2; ++mi) {
    float rinv[4];
#pragma unroll
    for (int r = 0; r < 4; ++r) rinv[r] = 1.f / l_run[mi][r];
#pragma unroll
    for (int db = 0; db < 8; ++db)
#pragma unroll
      for (int r = 0; r < 4; ++r) {
        int gr = q0 + w * 32 + mi * 16 + 4 * g + r;
        if (gr < L_SEQ)
          ao[(size_t)gr * DIMSZ + h * HDIM + db * 16 + ln] = acc_o[mi][db][r] * rinv[r];
      }
  }
}

extern "C" void kernel_launch(void* const* d_in, const int* in_sizes, int n_in,
                              void* d_out, int out_size, void* d_ws, size_t ws_size,
                              hipStream_t stream) {
  const float* x  = (const float*)d_in[0];
  const float* wq = (const float*)d_in[1];
  const float* bq = (const float*)d_in[2];
  const float* wk = (const float*)d_in[3];
  const float* bk = (const float*)d_in[4];
  const float* wv = (const float*)d_in[5];
  const float* bv = (const float*)d_in[6];
  const float* wo = (const float*)d_in[7];
  const float* bo = (const float*)d_in[8];
  const float* gq = (const float*)d_in[9];
  const float* gk = (const float*)d_in[10];
  const float* freqs = (const float*)d_in[11];
  float* out = (float*)d_out;
  float* ws = (float*)d_ws;
  const size_t LD = (size_t)L_SEQ * DIMSZ;
  float* q  = ws;
  float* k  = ws + LD;
  float* v  = ws + 2 * LD;
  float* ao = ws + 3 * LD;

  dim3 blk(256);
  dim3 ggrid((L_SEQ + 127) / 128, DIMSZ / 128);
  gemm_mfma<<<ggrid, blk, 0, stream>>>(x, wq, bq, q, L_SEQ);
  gemm_mfma<<<ggrid, blk, 0, stream>>>(x, wk, bk, k, L_SEQ);
  gemm_mfma<<<ggrid, blk, 0, stream>>>(x, wv, bv, v, L_SEQ);
  norm_rope<<<dim3(L_SEQ, 2), blk, 0, stream>>>(q, k, gq, gk, freqs);
  attn_mfma<<<dim3((L_SEQ + 127) / 128, NHEAD), blk, 0, stream>>>(q, k, v, ao);
  gemm_mfma<<<ggrid, blk, 0, stream>>>(ao, wo, bo, out, L_SEQ);
}

// Round 3
// 1037.644 us; speedup vs baseline: 3.9984x; 1.5580x over previous
//
#include <hip/hip_runtime.h>

#define L_SEQ 4680
#define DIMSZ 1536
#define NHEAD 12
#define HDIM 128
#define FRAME 1560
#define SCALE 0.08838834764831845f  // 1/sqrt(128)

typedef float f32x4 __attribute__((ext_vector_type(4)));
typedef short s16x8 __attribute__((ext_vector_type(8)));
typedef _Float16 f16;
typedef _Float16 f16x8 __attribute__((ext_vector_type(8)));

__device__ __forceinline__ unsigned short f2bf(float f) {
  unsigned u = __float_as_uint(f);
  unsigned r = u + 0x7fffu + ((u >> 16) & 1u);
  return (unsigned short)(r >> 16);
}
__device__ __forceinline__ float bf2f(unsigned short h) {
  return __uint_as_float(((unsigned)h) << 16);
}

// ============ GEMM: C[M][1536] = A[M][1536] * W[1536][1536]^T + bias ============
// bf16 hi/lo split, 3-pass MFMA. 128x128 tile, BK=64, 4 waves (2x2). (unchanged)
__global__ __launch_bounds__(256) void gemm_mfma(
    const float* __restrict__ A, const float* __restrict__ Wt,
    const float* __restrict__ bias, float* __restrict__ C, int M) {
  __shared__ unsigned short Ah[128 * 64];
  __shared__ unsigned short Al[128 * 64];
  __shared__ unsigned short Bh[128 * 64];
  __shared__ unsigned short Bl[128 * 64];
  const int t = threadIdx.x;
  const int lane = t & 63, w = t >> 6;
  const int g = lane >> 4, ln = lane & 15;
  const int wm = w >> 1, wn = w & 1;
  const int bm0 = blockIdx.x * 128, bn0 = blockIdx.y * 128;
  f32x4 acc[4][4] = {};

  for (int k0 = 0; k0 < DIMSZ; k0 += 64) {
    __syncthreads();
#pragma unroll
    for (int pass = 0; pass < 4; ++pass) {
      int ch = t + 256 * pass;
      int row = ch >> 3, s = ch & 7;
      int off = row * 64 + ((s * 8) ^ ((row & 7) * 8));
      {
        int gr = min(bm0 + row, M - 1);
        const float* src = &A[(size_t)gr * DIMSZ + k0 + s * 8];
        float4 v0 = *(const float4*)src, v1 = *(const float4*)(src + 4);
        float f[8] = {v0.x, v0.y, v0.z, v0.w, v1.x, v1.y, v1.z, v1.w};
        union { unsigned short h[8]; float4 q; } uh, ul;
#pragma unroll
        for (int i = 0; i < 8; ++i) {
          unsigned short hb = f2bf(f[i]);
          uh.h[i] = hb;
          ul.h[i] = f2bf(f[i] - bf2f(hb));
        }
        *(float4*)&Ah[off] = uh.q;
        *(float4*)&Al[off] = ul.q;
      }
      {
        int gr = bn0 + row;
        const float* src = &Wt[(size_t)gr * DIMSZ + k0 + s * 8];
        float4 v0 = *(const float4*)src, v1 = *(const float4*)(src + 4);
        float f[8] = {v0.x, v0.y, v0.z, v0.w, v1.x, v1.y, v1.z, v1.w};
        union { unsigned short h[8]; float4 q; } uh, ul;
#pragma unroll
        for (int i = 0; i < 8; ++i) {
          unsigned short hb = f2bf(f[i]);
          uh.h[i] = hb;
          ul.h[i] = f2bf(f[i] - bf2f(hb));
        }
        *(float4*)&Bh[off] = uh.q;
        *(float4*)&Bl[off] = ul.q;
      }
    }
    __syncthreads();
#pragma unroll
    for (int kc = 0; kc < 2; ++kc) {
      s16x8 ah[4], al[4], bh[4], bl[4];
#pragma unroll
      for (int mi = 0; mi < 4; ++mi) {
        int row = wm * 64 + mi * 16 + ln;
        int off = row * 64 + ((g * 8 + kc * 32) ^ ((row & 7) * 8));
        ah[mi] = *(const s16x8*)&Ah[off];
        al[mi] = *(const s16x8*)&Al[off];
      }
#pragma unroll
      for (int ni = 0; ni < 4; ++ni) {
        int row = wn * 64 + ni * 16 + ln;
        int off = row * 64 + ((g * 8 + kc * 32) ^ ((row & 7) * 8));
        bh[ni] = *(const s16x8*)&Bh[off];
        bl[ni] = *(const s16x8*)&Bl[off];
      }
#pragma unroll
      for (int mi = 0; mi < 4; ++mi)
#pragma unroll
        for (int ni = 0; ni < 4; ++ni) {
          acc[mi][ni] = __builtin_amdgcn_mfma_f32_16x16x32_bf16(ah[mi], bh[ni], acc[mi][ni], 0, 0, 0);
          acc[mi][ni] = __builtin_amdgcn_mfma_f32_16x16x32_bf16(ah[mi], bl[ni], acc[mi][ni], 0, 0, 0);
          acc[mi][ni] = __builtin_amdgcn_mfma_f32_16x16x32_bf16(al[mi], bh[ni], acc[mi][ni], 0, 0, 0);
        }
    }
  }
#pragma unroll
  for (int mi = 0; mi < 4; ++mi)
#pragma unroll
    for (int ni = 0; ni < 4; ++ni) {
      int col = bn0 + wn * 64 + ni * 16 + ln;
      float bv = bias[col];
#pragma unroll
      for (int r = 0; r < 4; ++r) {
        int row = bm0 + wm * 64 + mi * 16 + 4 * g + r;
        if (row < M) C[(size_t)row * DIMSZ + col] = acc[mi][ni][r] + bv;
      }
    }
}

// ------------- fused RMSNorm + RoPE, in-place on q (y=0) / k (y=1) (unchanged) -------------
__global__ __launch_bounds__(256) void norm_rope(
    float* __restrict__ q, float* __restrict__ k,
    const float* __restrict__ gq, const float* __restrict__ gk,
    const float* __restrict__ freqs) {
  const int pos = blockIdx.x;
  float* row = (blockIdx.y == 0 ? q : k) + (size_t)pos * DIMSZ;
  const float* g = blockIdx.y == 0 ? gq : gk;
  const int t = threadIdx.x;
  float2 ab[3];
  float ss = 0.f;
#pragma unroll
  for (int i = 0; i < 3; ++i) {
    ab[i] = *(const float2*)&row[2 * (t + 256 * i)];
    ss += ab[i].x * ab[i].x + ab[i].y * ab[i].y;
  }
#pragma unroll
  for (int m = 32; m; m >>= 1) ss += __shfl_xor(ss, m);
  __shared__ float part[4];
  if ((t & 63) == 0) part[t >> 6] = ss;
  __syncthreads();
  const float tot = part[0] + part[1] + part[2] + part[3];
  const float scale = rsqrtf(tot * (1.f / DIMSZ) + 1e-6f);
  const int f = pos / FRAME;
  const int rem = pos - f * FRAME;
  const int hh = rem / 52;
  const int ww = rem - hh * 52;
#pragma unroll
  for (int i = 0; i < 3; ++i) {
    const int p = t + 256 * i;
    const int c = p & 63;
    const int pr = c < 22 ? f : (c < 43 ? hh : ww);
    const float cs = freqs[(pr * 64 + c) * 2 + 0];
    const float sn = freqs[(pr * 64 + c) * 2 + 1];
    const float a = ab[i].x * scale * g[2 * p];
    const float b = ab[i].y * scale * g[2 * p + 1];
    float2 o;
    o.x = a * cs - b * sn;
    o.y = a * sn + b * cs;
    *(float2*)&row[2 * p] = o;
  }
}

// ============ flash attention v2: Q in registers, 48KB LDS, shared K/V fragments ============
__global__ __launch_bounds__(256, 2) void attn_mfma(
    const float* __restrict__ q, const float* __restrict__ k,
    const float* __restrict__ v, float* __restrict__ ao) {
  __shared__ f16 Ks[64 * 128];    // [key][d], swizzled, 16KB
  __shared__ f16 Vt[128 * 64];    // [d][key], swizzled, 16KB
  __shared__ f16 Ps[4 * 32 * 64]; // per-wave P, 16KB
  const int q0 = (gridDim.x - 1 - blockIdx.x) * 128;  // heavy tiles launch first
  const int h = blockIdx.y;
  const int t = threadIdx.x;
  const int lane = t & 63, w = t >> 6;
  const int g = lane >> 4, ln = lane & 15;

  // ---- Q fragments straight from global into registers (loop-invariant) ----
  f16x8 qa[2][4];
#pragma unroll
  for (int mi = 0; mi < 2; ++mi) {
    int row = min(q0 + w * 32 + mi * 16 + ln, L_SEQ - 1);
    const float* base = &q[(size_t)row * DIMSZ + h * HDIM + g * 8];
#pragma unroll
    for (int kc = 0; kc < 4; ++kc) {
      float4 v0 = *(const float4*)(base + kc * 32);
      float4 v1 = *(const float4*)(base + kc * 32 + 4);
      f16x8 u;
      u[0] = (f16)v0.x; u[1] = (f16)v0.y; u[2] = (f16)v0.z; u[3] = (f16)v0.w;
      u[4] = (f16)v1.x; u[5] = (f16)v1.y; u[6] = (f16)v1.z; u[7] = (f16)v1.w;
      qa[mi][kc] = u;
    }
  }

  float m_run[2][4], l_run[2][4];
  f32x4 acc_o[2][8] = {};
  int klim[2][4];
#pragma unroll
  for (int mi = 0; mi < 2; ++mi)
#pragma unroll
    for (int r = 0; r < 4; ++r) {
      m_run[mi][r] = -1e30f;
      l_run[mi][r] = 0.f;
      int gr = min(q0 + w * 32 + mi * 16 + 4 * g + r, L_SEQ - 1);
      klim[mi][r] = (gr / FRAME + 1) * FRAME;
    }
  const int rmax = min(q0 + 127, L_SEQ - 1);
  const int kend = (rmax / FRAME + 1) * FRAME;

  for (int k0 = 0; k0 < kend; k0 += 64) {
    __syncthreads();
    // ---- stage K tile (fp16, swizzled) ----
#pragma unroll
    for (int pass = 0; pass < 4; ++pass) {
      int ch = t + 256 * pass;
      int row = ch >> 4, s = ch & 15;
      int gc = min(k0 + row, L_SEQ - 1);
      const float* src = &k[(size_t)gc * DIMSZ + h * HDIM + s * 8];
      float4 v0 = *(const float4*)src, v1 = *(const float4*)(src + 4);
      union { f16 hh[8]; float4 f; } u;
      u.hh[0] = (f16)v0.x; u.hh[1] = (f16)v0.y; u.hh[2] = (f16)v0.z; u.hh[3] = (f16)v0.w;
      u.hh[4] = (f16)v1.x; u.hh[5] = (f16)v1.y; u.hh[6] = (f16)v1.z; u.hh[7] = (f16)v1.w;
      *(float4*)&Ks[row * 128 + ((s * 8) ^ ((row & 7) * 8))] = u.f;
    }
    // ---- stage V transposed ----
#pragma unroll
    for (int pass = 0; pass < 8; ++pass) {
      int kk = t & 63;
      int db = (t >> 6) * 4 + pass * 16;
      int gc = min(k0 + kk, L_SEQ - 1);
      float4 vv = *(const float4*)&v[(size_t)gc * DIMSZ + h * HDIM + db];
      float f[4] = {vv.x, vv.y, vv.z, vv.w};
#pragma unroll
      for (int i = 0; i < 4; ++i) {
        int d = db + i;
        Vt[d * 64 + (kk ^ ((d & 7) * 8))] = (f16)f[i];
      }
    }
    __syncthreads();

    // ---- S = Q K^T for both mi strips; K fragments shared across mi ----
    f32x4 sacc[2][4] = {};
    __builtin_amdgcn_s_setprio(1);
#pragma unroll
    for (int nb = 0; nb < 4; ++nb) {
      int row = nb * 16 + ln;
      f16x8 kb[4];
#pragma unroll
      for (int kc = 0; kc < 4; ++kc)
        kb[kc] = *(const f16x8*)&Ks[row * 128 + ((g * 8 + kc * 32) ^ ((row & 7) * 8))];
#pragma unroll
      for (int kc = 0; kc < 4; ++kc) {
        sacc[0][nb] = __builtin_amdgcn_mfma_f32_16x16x32_f16(qa[0][kc], kb[kc], sacc[0][nb], 0, 0, 0);
        sacc[1][nb] = __builtin_amdgcn_mfma_f32_16x16x32_f16(qa[1][kc], kb[kc], sacc[1][nb], 0, 0, 0);
      }
    }
    __builtin_amdgcn_s_setprio(0);

    // ---- online softmax per mi; P -> per-wave LDS ----
    float fs[2][4];
#pragma unroll
    for (int mi = 0; mi < 2; ++mi) {
      float p[4][4], rowmax[4];
#pragma unroll
      for (int r = 0; r < 4; ++r) rowmax[r] = -1e30f;
#pragma unroll
      for (int nb = 0; nb < 4; ++nb) {
        int gc = k0 + nb * 16 + ln;
#pragma unroll
        for (int r = 0; r < 4; ++r) {
          float val = sacc[mi][nb][r] * SCALE;
          if (gc >= klim[mi][r]) val = -1e30f;
          p[nb][r] = val;
          rowmax[r] = fmaxf(rowmax[r], val);
        }
      }
#pragma unroll
      for (int msk = 1; msk < 16; msk <<= 1)
#pragma unroll
        for (int r = 0; r < 4; ++r) rowmax[r] = fmaxf(rowmax[r], __shfl_xor(rowmax[r], msk));
      float rsum[4];
#pragma unroll
      for (int r = 0; r < 4; ++r) {
        float mn = fmaxf(m_run[mi][r], rowmax[r]);
        fs[mi][r] = __expf(m_run[mi][r] - mn);
        m_run[mi][r] = mn;
        float sm = 0.f;
#pragma unroll
        for (int nb = 0; nb < 4; ++nb) {
          float e = __expf(p[nb][r] - mn);
          p[nb][r] = e;
          sm += e;
        }
        rsum[r] = sm;
      }
#pragma unroll
      for (int msk = 1; msk < 16; msk <<= 1)
#pragma unroll
        for (int r = 0; r < 4; ++r) rsum[r] += __shfl_xor(rsum[r], msk);
#pragma unroll
      for (int r = 0; r < 4; ++r) l_run[mi][r] = l_run[mi][r] * fs[mi][r] + rsum[r];
      // write P (fp16) into per-wave LDS region
#pragma unroll
      for (int nb = 0; nb < 4; ++nb)
#pragma unroll
        for (int r = 0; r < 4; ++r) {
          int row = mi * 16 + 4 * g + r;
          Ps[w * 2048 + row * 64 + ((nb * 16 + ln) ^ ((row & 7) * 8))] = (f16)p[nb][r];
        }
    }
    // rescale acc
#pragma unroll
    for (int mi = 0; mi < 2; ++mi)
#pragma unroll
      for (int db = 0; db < 8; ++db)
#pragma unroll
        for (int r = 0; r < 4; ++r) acc_o[mi][db][r] *= fs[mi][r];

    // ---- PV; V fragments shared across mi ----
    f16x8 pa[2][2];
#pragma unroll
    for (int mi = 0; mi < 2; ++mi) {
      int row = mi * 16 + ln;
#pragma unroll
      for (int kc = 0; kc < 2; ++kc)
        pa[mi][kc] = *(const f16x8*)&Ps[w * 2048 + row * 64 + ((kc * 32 + g * 8) ^ ((row & 7) * 8))];
    }
    __builtin_amdgcn_s_setprio(1);
#pragma unroll
    for (int db = 0; db < 8; ++db) {
      int d = db * 16 + ln;
      f16x8 vb[2];
#pragma unroll
      for (int kc = 0; kc < 2; ++kc)
        vb[kc] = *(const f16x8*)&Vt[d * 64 + ((kc * 32 + g * 8) ^ ((d & 7) * 8))];
#pragma unroll
      for (int kc = 0; kc < 2; ++kc) {
        acc_o[0][db] = __builtin_amdgcn_mfma_f32_16x16x32_f16(pa[0][kc], vb[kc], acc_o[0][db], 0, 0, 0);
        acc_o[1][db] = __builtin_amdgcn_mfma_f32_16x16x32_f16(pa[1][kc], vb[kc], acc_o[1][db], 0, 0, 0);
      }
    }
    __builtin_amdgcn_s_setprio(0);
  }

  // ---- epilogue ----
#pragma unroll
  for (int mi = 0; mi < 2; ++mi) {
    float rinv[4];
#pragma unroll
    for (int r = 0; r < 4; ++r) rinv[r] = 1.f / l_run[mi][r];
#pragma unroll
    for (int db = 0; db < 8; ++db)
#pragma unroll
      for (int r = 0; r < 4; ++r) {
        int gr = q0 + w * 32 + mi * 16 + 4 * g + r;
        if (gr < L_SEQ)
          ao[(size_t)gr * DIMSZ + h * HDIM + db * 16 + ln] = acc_o[mi][db][r] * rinv[r];
      }
  }
}

extern "C" void kernel_launch(void* const* d_in, const int* in_sizes, int n_in,
                              void* d_out, int out_size, void* d_ws, size_t ws_size,
                              hipStream_t stream) {
  const float* x  = (const float*)d_in[0];
  const float* wq = (const float*)d_in[1];
  const float* bq = (const float*)d_in[2];
  const float* wk = (const float*)d_in[3];
  const float* bk = (const float*)d_in[4];
  const float* wv = (const float*)d_in[5];
  const float* bv = (const float*)d_in[6];
  const float* wo = (const float*)d_in[7];
  const float* bo = (const float*)d_in[8];
  const float* gq = (const float*)d_in[9];
  const float* gk = (const float*)d_in[10];
  const float* freqs = (const float*)d_in[11];
  float* out = (float*)d_out;
  float* ws = (float*)d_ws;
  const size_t LD = (size_t)L_SEQ * DIMSZ;
  float* q  = ws;
  float* k  = ws + LD;
  float* v  = ws + 2 * LD;
  float* ao = ws + 3 * LD;

  dim3 blk(256);
  dim3 ggrid((L_SEQ + 127) / 128, DIMSZ / 128);
  gemm_mfma<<<ggrid, blk, 0, stream>>>(x, wq, bq, q, L_SEQ);
  gemm_mfma<<<ggrid, blk, 0, stream>>>(x, wk, bk, k, L_SEQ);
  gemm_mfma<<<ggrid, blk, 0, stream>>>(x, wv, bv, v, L_SEQ);
  norm_rope<<<dim3(L_SEQ, 2), blk, 0, stream>>>(q, k, gq, gk, freqs);
  attn_mfma<<<dim3((L_SEQ + 127) / 128, NHEAD), blk, 0, stream>>>(q, k, v, ao);
  gemm_mfma<<<ggrid, blk, 0, stream>>>(ao, wo, bo, out, L_SEQ);
}

// Round 4
// 867.866 us; speedup vs baseline: 4.7806x; 1.1956x over previous
//
#include <hip/hip_runtime.h>

#define L_SEQ 4680
#define DIMSZ 1536
#define NHEAD 12
#define HDIM 128
#define FRAME 1560
#define NKT_ALL 74            // ceil(4680/64)
#define SCALE_L2E 0.12751743f // (1/sqrt(128)) * log2(e)

typedef float f32x4 __attribute__((ext_vector_type(4)));
typedef short s16x8 __attribute__((ext_vector_type(8)));
typedef _Float16 f16;
typedef _Float16 f16x2 __attribute__((ext_vector_type(2)));
typedef _Float16 f16x4 __attribute__((ext_vector_type(4)));
typedef _Float16 f16x8 __attribute__((ext_vector_type(8)));

__device__ __forceinline__ unsigned short f2bf(float f) {
  unsigned u = __float_as_uint(f);
  unsigned r = u + 0x7fffu + ((u >> 16) & 1u);
  return (unsigned short)(r >> 16);
}
__device__ __forceinline__ float bf2f(unsigned short h) {
  return __uint_as_float(((unsigned)h) << 16);
}

__device__ __forceinline__ void gll16(const f16* g, const f16* l) {
  __builtin_amdgcn_global_load_lds(
      (const __attribute__((address_space(1))) unsigned int*)g,
      (__attribute__((address_space(3))) unsigned int*)l, 16, 0, 0);
}

// ============ GEMM: C[M][1536] = A[M][1536] * W[1536][1536]^T + bias (unchanged) ============
__global__ __launch_bounds__(256) void gemm_mfma(
    const float* __restrict__ A, const float* __restrict__ Wt,
    const float* __restrict__ bias, float* __restrict__ C, int M) {
  __shared__ unsigned short Ah[128 * 64];
  __shared__ unsigned short Al[128 * 64];
  __shared__ unsigned short Bh[128 * 64];
  __shared__ unsigned short Bl[128 * 64];
  const int t = threadIdx.x;
  const int lane = t & 63, w = t >> 6;
  const int g = lane >> 4, ln = lane & 15;
  const int wm = w >> 1, wn = w & 1;
  const int bm0 = blockIdx.x * 128, bn0 = blockIdx.y * 128;
  f32x4 acc[4][4] = {};

  for (int k0 = 0; k0 < DIMSZ; k0 += 64) {
    __syncthreads();
#pragma unroll
    for (int pass = 0; pass < 4; ++pass) {
      int ch = t + 256 * pass;
      int row = ch >> 3, s = ch & 7;
      int off = row * 64 + ((s * 8) ^ ((row & 7) * 8));
      {
        int gr = min(bm0 + row, M - 1);
        const float* src = &A[(size_t)gr * DIMSZ + k0 + s * 8];
        float4 v0 = *(const float4*)src, v1 = *(const float4*)(src + 4);
        float f[8] = {v0.x, v0.y, v0.z, v0.w, v1.x, v1.y, v1.z, v1.w};
        union { unsigned short h[8]; float4 q; } uh, ul;
#pragma unroll
        for (int i = 0; i < 8; ++i) {
          unsigned short hb = f2bf(f[i]);
          uh.h[i] = hb;
          ul.h[i] = f2bf(f[i] - bf2f(hb));
        }
        *(float4*)&Ah[off] = uh.q;
        *(float4*)&Al[off] = ul.q;
      }
      {
        int gr = bn0 + row;
        const float* src = &Wt[(size_t)gr * DIMSZ + k0 + s * 8];
        float4 v0 = *(const float4*)src, v1 = *(const float4*)(src + 4);
        float f[8] = {v0.x, v0.y, v0.z, v0.w, v1.x, v1.y, v1.z, v1.w};
        union { unsigned short h[8]; float4 q; } uh, ul;
#pragma unroll
        for (int i = 0; i < 8; ++i) {
          unsigned short hb = f2bf(f[i]);
          uh.h[i] = hb;
          ul.h[i] = f2bf(f[i] - bf2f(hb));
        }
        *(float4*)&Bh[off] = uh.q;
        *(float4*)&Bl[off] = ul.q;
      }
    }
    __syncthreads();
#pragma unroll
    for (int kc = 0; kc < 2; ++kc) {
      s16x8 ah[4], al[4], bh[4], bl[4];
#pragma unroll
      for (int mi = 0; mi < 4; ++mi) {
        int row = wm * 64 + mi * 16 + ln;
        int off = row * 64 + ((g * 8 + kc * 32) ^ ((row & 7) * 8));
        ah[mi] = *(const s16x8*)&Ah[off];
        al[mi] = *(const s16x8*)&Al[off];
      }
#pragma unroll
      for (int ni = 0; ni < 4; ++ni) {
        int row = wn * 64 + ni * 16 + ln;
        int off = row * 64 + ((g * 8 + kc * 32) ^ ((row & 7) * 8));
        bh[ni] = *(const s16x8*)&Bh[off];
        bl[ni] = *(const s16x8*)&Bl[off];
      }
#pragma unroll
      for (int mi = 0; mi < 4; ++mi)
#pragma unroll
        for (int ni = 0; ni < 4; ++ni) {
          acc[mi][ni] = __builtin_amdgcn_mfma_f32_16x16x32_bf16(ah[mi], bh[ni], acc[mi][ni], 0, 0, 0);
          acc[mi][ni] = __builtin_amdgcn_mfma_f32_16x16x32_bf16(ah[mi], bl[ni], acc[mi][ni], 0, 0, 0);
          acc[mi][ni] = __builtin_amdgcn_mfma_f32_16x16x32_bf16(al[mi], bh[ni], acc[mi][ni], 0, 0, 0);
        }
    }
  }
#pragma unroll
  for (int mi = 0; mi < 4; ++mi)
#pragma unroll
    for (int ni = 0; ni < 4; ++ni) {
      int col = bn0 + wn * 64 + ni * 16 + ln;
      float bv = bias[col];
#pragma unroll
      for (int r = 0; r < 4; ++r) {
        int row = bm0 + wm * 64 + mi * 16 + 4 * g + r;
        if (row < M) C[(size_t)row * DIMSZ + col] = acc[mi][ni][r] + bv;
      }
    }
}

// ------------- RMSNorm + RoPE -> fp16 outputs. y=0: q16 [L][1536] (pre-scaled);
// ------------- y=1: k16 blocked [head][tile][64][128] with LDS swizzle baked in -------------
__global__ __launch_bounds__(256) void norm_rope(
    const float* __restrict__ qf, const float* __restrict__ kf,
    const float* __restrict__ gq, const float* __restrict__ gk,
    const float* __restrict__ freqs, f16* __restrict__ q16, f16* __restrict__ k16) {
  const int pos = blockIdx.x;
  const bool isq = blockIdx.y == 0;
  const float* row = (isq ? qf : kf) + (size_t)pos * DIMSZ;
  const float* g = isq ? gq : gk;
  const int t = threadIdx.x;
  float2 ab[3];
  float ss = 0.f;
#pragma unroll
  for (int i = 0; i < 3; ++i) {
    ab[i] = *(const float2*)&row[2 * (t + 256 * i)];
    ss += ab[i].x * ab[i].x + ab[i].y * ab[i].y;
  }
#pragma unroll
  for (int m = 32; m; m >>= 1) ss += __shfl_xor(ss, m);
  __shared__ float part[4];
  if ((t & 63) == 0) part[t >> 6] = ss;
  __syncthreads();
  const float tot = part[0] + part[1] + part[2] + part[3];
  float scale = rsqrtf(tot * (1.f / DIMSZ) + 1e-6f);
  if (isq) scale *= SCALE_L2E;
  const int f = pos / FRAME;
  const int rem = pos - f * FRAME;
  const int hh = rem / 52;
  const int ww = rem - hh * 52;
  const int kt = pos >> 6, kk = pos & 63;
#pragma unroll
  for (int i = 0; i < 3; ++i) {
    const int p = t + 256 * i;     // pair index 0..767
    const int c = p & 63;          // pair within head
    const int h = p >> 6;
    const int pr = c < 22 ? f : (c < 43 ? hh : ww);
    const float cs = freqs[(pr * 64 + c) * 2 + 0];
    const float sn = freqs[(pr * 64 + c) * 2 + 1];
    const float a = ab[i].x * scale * g[2 * p];
    const float b = ab[i].y * scale * g[2 * p + 1];
    f16x2 o;
    o[0] = (f16)(a * cs - b * sn);
    o[1] = (f16)(a * sn + b * cs);
    if (isq) {
      *(f16x2*)&q16[(size_t)pos * DIMSZ + 2 * p] = o;
    } else {
      const int s = c >> 2;        // 16B chunk within head row
      size_t base = ((size_t)(h * NKT_ALL + kt)) << 13;
      *(f16x2*)&k16[base + kk * 128 + ((s * 8) ^ ((kk & 7) * 8)) + (c & 3) * 2] = o;
    }
  }
}

// ------------- V -> fp16, transposed+swizzled blocked [head][tile][d=128][key=64] -------------
__global__ __launch_bounds__(256) void vconvert(const float* __restrict__ v, f16* __restrict__ v16) {
  __shared__ f16 Ls[64][136];
  const int kt = blockIdx.x, h = blockIdx.y, t = threadIdx.x;
#pragma unroll
  for (int p = 0; p < 8; ++p) {
    int e = p * 1024 + t * 4;
    int kk = e >> 7, d = e & 127;
    int gr = kt * 64 + kk;
    float4 val = make_float4(0.f, 0.f, 0.f, 0.f);
    if (gr < L_SEQ) val = *(const float4*)&v[(size_t)gr * DIMSZ + h * HDIM + d];
    f16x4 o;
    o[0] = (f16)val.x; o[1] = (f16)val.y; o[2] = (f16)val.z; o[3] = (f16)val.w;
    *(f16x4*)&Ls[kk][d] = o;
  }
  __syncthreads();
  f16* out = v16 + (((size_t)(h * NKT_ALL + kt)) << 13);
#pragma unroll
  for (int p = 0; p < 4; ++p) {
    int idx = p * 256 + t;
    int d = idx >> 3, kg = idx & 7;
    f16x8 o;
#pragma unroll
    for (int i = 0; i < 8; ++i) o[i] = Ls[kg * 8 + i][d];
    *(f16x8*)&out[d * 64 + ((kg * 8) ^ ((d & 7) * 8))] = o;
  }
}

// ============ flash attention v3: 64-row tiles, global_load_lds, 2-phase dbuf ============
__global__ __launch_bounds__(256, 2) void attn_mfma(
    const f16* __restrict__ q16, const f16* __restrict__ k16,
    const f16* __restrict__ v16, float* __restrict__ ao) {
  __shared__ f16 Ks[2][8192];   // [key=64][d=128] swizzled, 16KB each
  __shared__ f16 Vt[2][8192];   // [d=128][key=64] swizzled
  __shared__ f16 Ps[4][1024];   // per-wave P [16][64] swizzled
  const int tile = (int)gridDim.x - 1 - (int)blockIdx.x;  // heavy first
  const int q0 = tile * 64;
  const int h = blockIdx.y;
  const int t = threadIdx.x;
  const int lane = t & 63, w = t >> 6;
  const int g = lane >> 4, ln = lane & 15;

  // Q fragments from global (pre-scaled fp16)
  f16x8 qa[4];
  {
    int qrow = min(q0 + w * 16 + ln, L_SEQ - 1);
    const f16* qb = &q16[(size_t)qrow * DIMSZ + h * HDIM + g * 8];
#pragma unroll
    for (int kc = 0; kc < 4; ++kc) qa[kc] = *(const f16x8*)&qb[kc * 32];
  }

  float m_run[4], l_run[4];
  int klim[4];
  f32x4 acc_o[8] = {};
#pragma unroll
  for (int r = 0; r < 4; ++r) {
    m_run[r] = -1e30f;
    l_run[r] = 0.f;
    int gr = min(q0 + w * 16 + 4 * g + r, L_SEQ - 1);
    klim[r] = (gr / FRAME + 1) * FRAME;
  }
  const int rmax = min(q0 + 63, L_SEQ - 1);
  const int nkt = ((rmax / FRAME + 1) * FRAME + 63) >> 6;

  const size_t hbase = ((size_t)h * NKT_ALL) << 13;
  // prologue: stage tile 0 into buffer 0
#pragma unroll
  for (int i = 0; i < 4; ++i) {
    gll16(k16 + hbase + (i * 256 + t) * 8, &Ks[0][(i * 256 + t) * 8]);
    gll16(v16 + hbase + (i * 256 + t) * 8, &Vt[0][(i * 256 + t) * 8]);
  }

  int buf = 0;
  for (int kt = 0; kt < nkt; ++kt) {
    __syncthreads();  // drains vmcnt -> staged tile kt ready; all waves done with buf^1
    if (kt + 1 < nkt) {
      size_t tb = hbase + ((size_t)(kt + 1) << 13);
      int b = buf ^ 1;
#pragma unroll
      for (int i = 0; i < 4; ++i) {
        gll16(k16 + tb + (i * 256 + t) * 8, &Ks[b][(i * 256 + t) * 8]);
        gll16(v16 + tb + (i * 256 + t) * 8, &Vt[b][(i * 256 + t) * 8]);
      }
    }
    const f16* Kb = Ks[buf];
    const f16* Vb = Vt[buf];

    // ---- S = Q K^T ----
    f32x4 sacc[4] = {};
    __builtin_amdgcn_s_setprio(1);
#pragma unroll
    for (int nb = 0; nb < 4; ++nb) {
      int row = nb * 16 + ln;
#pragma unroll
      for (int kc = 0; kc < 4; ++kc) {
        f16x8 kb = *(const f16x8*)&Kb[row * 128 + ((g * 8 + kc * 32) ^ ((row & 7) * 8))];
        sacc[nb] = __builtin_amdgcn_mfma_f32_16x16x32_f16(qa[kc], kb, sacc[nb], 0, 0, 0);
      }
    }
    __builtin_amdgcn_s_setprio(0);

    // ---- online softmax (base-2) ----
    float p[4][4], rowmax[4];
#pragma unroll
    for (int r = 0; r < 4; ++r) rowmax[r] = -1e30f;
#pragma unroll
    for (int nb = 0; nb < 4; ++nb) {
      int gc = kt * 64 + nb * 16 + ln;
#pragma unroll
      for (int r = 0; r < 4; ++r) {
        float val = sacc[nb][r];
        if (gc >= klim[r]) val = -1e30f;
        p[nb][r] = val;
        rowmax[r] = fmaxf(rowmax[r], val);
      }
    }
#pragma unroll
    for (int msk = 1; msk < 16; msk <<= 1)
#pragma unroll
      for (int r = 0; r < 4; ++r) rowmax[r] = fmaxf(rowmax[r], __shfl_xor(rowmax[r], msk));
    float fs[4], rsum[4];
#pragma unroll
    for (int r = 0; r < 4; ++r) {
      float mn = fmaxf(m_run[r], rowmax[r]);
      fs[r] = exp2f(m_run[r] - mn);
      m_run[r] = mn;
      float sm = 0.f;
#pragma unroll
      for (int nb = 0; nb < 4; ++nb) {
        float e = exp2f(p[nb][r] - mn);
        p[nb][r] = e;
        sm += e;
      }
      rsum[r] = sm;
    }
#pragma unroll
    for (int msk = 1; msk < 16; msk <<= 1)
#pragma unroll
      for (int r = 0; r < 4; ++r) rsum[r] += __shfl_xor(rsum[r], msk);
#pragma unroll
    for (int r = 0; r < 4; ++r) l_run[r] = l_run[r] * fs[r] + rsum[r];
#pragma unroll
    for (int db = 0; db < 8; ++db)
#pragma unroll
      for (int r = 0; r < 4; ++r) acc_o[db][r] *= fs[r];

    // P -> per-wave LDS (fp16)
#pragma unroll
    for (int nb = 0; nb < 4; ++nb)
#pragma unroll
      for (int r = 0; r < 4; ++r) {
        int row = 4 * g + r;
        Ps[w][row * 64 + ((nb * 16 + ln) ^ ((row & 7) * 8))] = (f16)p[nb][r];
      }
    f16x8 pa[2];
#pragma unroll
    for (int kc = 0; kc < 2; ++kc)
      pa[kc] = *(const f16x8*)&Ps[w][ln * 64 + ((kc * 32 + g * 8) ^ ((ln & 7) * 8))];

    // ---- PV ----
    __builtin_amdgcn_s_setprio(1);
#pragma unroll
    for (int db = 0; db < 8; ++db) {
      int d = db * 16 + ln;
#pragma unroll
      for (int kc = 0; kc < 2; ++kc) {
        f16x8 vb = *(const f16x8*)&Vb[d * 64 + ((kc * 32 + g * 8) ^ ((d & 7) * 8))];
        acc_o[db] = __builtin_amdgcn_mfma_f32_16x16x32_f16(pa[kc], vb, acc_o[db], 0, 0, 0);
      }
    }
    __builtin_amdgcn_s_setprio(0);
    buf ^= 1;
  }

  // ---- epilogue ----
  float rinv[4];
#pragma unroll
  for (int r = 0; r < 4; ++r) rinv[r] = 1.f / l_run[r];
#pragma unroll
  for (int db = 0; db < 8; ++db)
#pragma unroll
    for (int r = 0; r < 4; ++r) {
      int gr = q0 + w * 16 + 4 * g + r;
      if (gr < L_SEQ)
        ao[(size_t)gr * DIMSZ + h * HDIM + db * 16 + ln] = acc_o[db][r] * rinv[r];
    }
}

extern "C" void kernel_launch(void* const* d_in, const int* in_sizes, int n_in,
                              void* d_out, int out_size, void* d_ws, size_t ws_size,
                              hipStream_t stream) {
  const float* x  = (const float*)d_in[0];
  const float* wq = (const float*)d_in[1];
  const float* bq = (const float*)d_in[2];
  const float* wk = (const float*)d_in[3];
  const float* bk = (const float*)d_in[4];
  const float* wv = (const float*)d_in[5];
  const float* bv = (const float*)d_in[6];
  const float* wo = (const float*)d_in[7];
  const float* bo = (const float*)d_in[8];
  const float* gq = (const float*)d_in[9];
  const float* gk = (const float*)d_in[10];
  const float* freqs = (const float*)d_in[11];
  float* out = (float*)d_out;
  float* ws = (float*)d_ws;
  const size_t LD = (size_t)L_SEQ * DIMSZ;
  float* qf = ws;
  float* kf = ws + LD;
  float* vf = ws + 2 * LD;
  f16* q16 = (f16*)(ws + 3 * LD);
  f16* k16 = q16 + LD;
  f16* v16 = k16 + (size_t)NHEAD * NKT_ALL * 8192;
  float* ao = qf;  // q fp32 dead after norm_rope; reuse for attention output

  dim3 blk(256);
  dim3 ggrid((L_SEQ + 127) / 128, DIMSZ / 128);
  gemm_mfma<<<ggrid, blk, 0, stream>>>(x, wq, bq, qf, L_SEQ);
  gemm_mfma<<<ggrid, blk, 0, stream>>>(x, wk, bk, kf, L_SEQ);
  gemm_mfma<<<ggrid, blk, 0, stream>>>(x, wv, bv, vf, L_SEQ);
  norm_rope<<<dim3(L_SEQ, 2), blk, 0, stream>>>(qf, kf, gq, gk, freqs, q16, k16);
  vconvert<<<dim3(NKT_ALL, NHEAD), blk, 0, stream>>>(vf, v16);
  attn_mfma<<<dim3(NKT_ALL, NHEAD), blk, 0, stream>>>(q16, k16, v16, ao);
  gemm_mfma<<<ggrid, blk, 0, stream>>>(ao, wo, bo, out, L_SEQ);
}

// Round 6
// 635.192 us; speedup vs baseline: 6.5317x; 1.3663x over previous
//
#include <hip/hip_runtime.h>

#define L_SEQ 4680
#define DIMSZ 1536
#define NHEAD 12
#define HDIM 128
#define FRAME 1560
#define NKT_ALL 74            // ceil(4680/64)
#define SCALE_L2E 0.12751743f // (1/sqrt(128)) * log2(e)

typedef float f32x4 __attribute__((ext_vector_type(4)));
typedef short s16x8 __attribute__((ext_vector_type(8)));
typedef _Float16 f16;
typedef _Float16 f16x2 __attribute__((ext_vector_type(2)));
typedef _Float16 f16x4 __attribute__((ext_vector_type(4)));
typedef _Float16 f16x8 __attribute__((ext_vector_type(8)));
typedef unsigned short u16;

__device__ __forceinline__ u16 f2bf(float f) {
  unsigned u = __float_as_uint(f);
  unsigned r = u + 0x7fffu + ((u >> 16) & 1u);
  return (u16)(r >> 16);
}
__device__ __forceinline__ float bf2f(u16 h) {
  return __uint_as_float(((unsigned)h) << 16);
}
__device__ __forceinline__ void gll16(const void* g, void* l) {
  __builtin_amdgcn_global_load_lds(
      (const __attribute__((address_space(1))) unsigned int*)g,
      (__attribute__((address_space(3))) unsigned int*)l, 16, 0, 0);
}

// ---- split fp32 [R][1536] -> bf16 hi/lo, blocked [rt][kt=48][128 rows][32 k] swizzled ----
__global__ __launch_bounds__(256) void split_bf16(
    const float* __restrict__ A, int R,
    u16* __restrict__ hi, u16* __restrict__ lo) {
  const int rt = blockIdx.x, kt = blockIdx.y;
  const int t = threadIdx.x;
  const int row = t >> 1, c0 = (t & 1) * 16;
  const int gr = min(rt * 128 + row, R - 1);
  const float* src = &A[(size_t)gr * DIMSZ + kt * 32 + c0];
  float f[16];
#pragma unroll
  for (int i = 0; i < 4; ++i) *(float4*)&f[i * 4] = *(const float4*)&src[i * 4];
  union { u16 h[8]; float4 q; } uh[2], ul[2];
#pragma unroll
  for (int i = 0; i < 16; ++i) {
    u16 hb = f2bf(f[i]);
    uh[i >> 3].h[i & 7] = hb;
    ul[i >> 3].h[i & 7] = f2bf(f[i] - bf2f(hb));
  }
  size_t obase = ((size_t)(rt * 48 + kt)) * 4096 + row * 32;
#pragma unroll
  for (int cc = 0; cc < 2; ++cc) {
    int s = (c0 >> 3) + cc;
    size_t off = obase + ((s * 8) ^ ((row & 3) * 8));
    *(float4*)&hi[off] = uh[cc].q;
    *(float4*)&lo[off] = ul[cc].q;
  }
}

// ---- GEMM from pre-split inputs: global_load_lds staging, BK=32, 2-phase dbuf ----
__global__ __launch_bounds__(256, 2) void gemm_split(
    const u16* __restrict__ Ah, const u16* __restrict__ Al,
    const u16* __restrict__ Bh, const u16* __restrict__ Bl,
    const float* __restrict__ bias, float* __restrict__ C, int M) {
  __shared__ u16 S[2][4][4096];  // [buf][Ah,Al,Bh,Bl][128x32 swizzled]
  const int t = threadIdx.x;
  const int lane = t & 63, w = t >> 6;
  const int g = lane >> 4, ln = lane & 15;
  const int wm = w >> 1, wn = w & 1;
  const int mt = blockIdx.x, nt = blockIdx.y;
  f32x4 acc[4][4] = {};
  const u16* srcs[4] = {Ah + (size_t)mt * 48 * 4096, Al + (size_t)mt * 48 * 4096,
                        Bh + (size_t)nt * 48 * 4096, Bl + (size_t)nt * 48 * 4096};
#pragma unroll
  for (int a = 0; a < 4; ++a)
#pragma unroll
    for (int i = 0; i < 2; ++i)
      gll16(srcs[a] + (i * 256 + t) * 8, &S[0][a][(i * 256 + t) * 8]);
  int buf = 0;
  for (int kt = 0; kt < 48; ++kt) {
    __syncthreads();
    if (kt + 1 < 48) {
      int b = buf ^ 1;
#pragma unroll
      for (int a = 0; a < 4; ++a)
#pragma unroll
        for (int i = 0; i < 2; ++i)
          gll16(srcs[a] + (size_t)(kt + 1) * 4096 + (i * 256 + t) * 8,
                &S[b][a][(i * 256 + t) * 8]);
    }
    s16x8 ah[4], al[4], bh[4], bl[4];
#pragma unroll
    for (int mi = 0; mi < 4; ++mi) {
      int row = wm * 64 + mi * 16 + ln;
      int off = row * 32 + ((g * 8) ^ ((row & 3) * 8));
      ah[mi] = *(const s16x8*)&S[buf][0][off];
      al[mi] = *(const s16x8*)&S[buf][1][off];
    }
#pragma unroll
    for (int ni = 0; ni < 4; ++ni) {
      int row = wn * 64 + ni * 16 + ln;
      int off = row * 32 + ((g * 8) ^ ((row & 3) * 8));
      bh[ni] = *(const s16x8*)&S[buf][2][off];
      bl[ni] = *(const s16x8*)&S[buf][3][off];
    }
#pragma unroll
    for (int mi = 0; mi < 4; ++mi)
#pragma unroll
      for (int ni = 0; ni < 4; ++ni) {
        acc[mi][ni] = __builtin_amdgcn_mfma_f32_16x16x32_bf16(ah[mi], bh[ni], acc[mi][ni], 0, 0, 0);
        acc[mi][ni] = __builtin_amdgcn_mfma_f32_16x16x32_bf16(ah[mi], bl[ni], acc[mi][ni], 0, 0, 0);
        acc[mi][ni] = __builtin_amdgcn_mfma_f32_16x16x32_bf16(al[mi], bh[ni], acc[mi][ni], 0, 0, 0);
      }
    buf ^= 1;
  }
#pragma unroll
  for (int mi = 0; mi < 4; ++mi)
#pragma unroll
    for (int ni = 0; ni < 4; ++ni) {
      int col = nt * 128 + wn * 64 + ni * 16 + ln;
      float bv = bias[col];
#pragma unroll
      for (int r = 0; r < 4; ++r) {
        int row = mt * 128 + wm * 64 + mi * 16 + 4 * g + r;
        if (row < M) C[(size_t)row * DIMSZ + col] = acc[mi][ni][r] + bv;
      }
    }
}

// ------------- RMSNorm + RoPE -> fp16. y=0: q16 [L][1536] pre-scaled; y=1: k16 blocked -------------
__global__ __launch_bounds__(256) void norm_rope(
    const float* __restrict__ qf, const float* __restrict__ kf,
    const float* __restrict__ gq, const float* __restrict__ gk,
    const float* __restrict__ freqs, f16* __restrict__ q16, f16* __restrict__ k16) {
  const int pos = blockIdx.x;
  const bool isq = blockIdx.y == 0;
  const float* row = (isq ? qf : kf) + (size_t)pos * DIMSZ;
  const float* g = isq ? gq : gk;
  const int t = threadIdx.x;
  float2 ab[3];
  float ss = 0.f;
#pragma unroll
  for (int i = 0; i < 3; ++i) {
    ab[i] = *(const float2*)&row[2 * (t + 256 * i)];
    ss += ab[i].x * ab[i].x + ab[i].y * ab[i].y;
  }
#pragma unroll
  for (int m = 32; m; m >>= 1) ss += __shfl_xor(ss, m);
  __shared__ float part[4];
  if ((t & 63) == 0) part[t >> 6] = ss;
  __syncthreads();
  const float tot = part[0] + part[1] + part[2] + part[3];
  float scale = rsqrtf(tot * (1.f / DIMSZ) + 1e-6f);
  if (isq) scale *= SCALE_L2E;
  const int f = pos / FRAME;
  const int rem = pos - f * FRAME;
  const int hh = rem / 52;
  const int ww = rem - hh * 52;
  const int kt = pos >> 6, kk = pos & 63;
#pragma unroll
  for (int i = 0; i < 3; ++i) {
    const int p = t + 256 * i;
    const int c = p & 63;
    const int h = p >> 6;
    const int pr = c < 22 ? f : (c < 43 ? hh : ww);
    const float cs = freqs[(pr * 64 + c) * 2 + 0];
    const float sn = freqs[(pr * 64 + c) * 2 + 1];
    const float a = ab[i].x * scale * g[2 * p];
    const float b = ab[i].y * scale * g[2 * p + 1];
    f16x2 o;
    o[0] = (f16)(a * cs - b * sn);
    o[1] = (f16)(a * sn + b * cs);
    if (isq) {
      *(f16x2*)&q16[(size_t)pos * DIMSZ + 2 * p] = o;
    } else {
      const int s = c >> 2;
      size_t base = ((size_t)(h * NKT_ALL + kt)) << 13;
      *(f16x2*)&k16[base + kk * 128 + ((s * 8) ^ ((kk & 7) * 8)) + (c & 3) * 2] = o;
    }
  }
}

// ------------- V -> fp16, transposed+swizzled blocked [head][tile][d=128][key=64] -------------
__global__ __launch_bounds__(256) void vconvert(const float* __restrict__ v, f16* __restrict__ v16) {
  __shared__ f16 Ls[64][136];
  const int kt = blockIdx.x, h = blockIdx.y, t = threadIdx.x;
#pragma unroll
  for (int p = 0; p < 8; ++p) {
    int e = p * 1024 + t * 4;
    int kk = e >> 7, d = e & 127;
    int gr = kt * 64 + kk;
    float4 val = make_float4(0.f, 0.f, 0.f, 0.f);
    if (gr < L_SEQ) val = *(const float4*)&v[(size_t)gr * DIMSZ + h * HDIM + d];
    f16x4 o;
    o[0] = (f16)val.x; o[1] = (f16)val.y; o[2] = (f16)val.z; o[3] = (f16)val.w;
    *(f16x4*)&Ls[kk][d] = o;
  }
  __syncthreads();
  f16* out = v16 + (((size_t)(h * NKT_ALL + kt)) << 13);
#pragma unroll
  for (int p = 0; p < 4; ++p) {
    int idx = p * 256 + t;
    int d = idx >> 3, kg = idx & 7;
    f16x8 o;
#pragma unroll
    for (int i = 0; i < 8; ++i) o[i] = Ls[kg * 8 + i][d];
    *(f16x8*)&out[d * 64 + ((kg * 8) ^ ((d & 7) * 8))] = o;
  }
}

// ============ flash attention v4: swapped QK^T (S^T), P in registers, O^T accum ============
__global__ __launch_bounds__(256, 2) void attn_mfma(
    const f16* __restrict__ q16, const f16* __restrict__ k16,
    const f16* __restrict__ v16, float* __restrict__ ao) {
  __shared__ f16 Ks[2][8192];   // [key=64][d=128] swizzled
  __shared__ f16 Vt[2][8192];   // [d=128][key=64] swizzled
  __shared__ float Os[4][16][20];
  const int tile = (int)gridDim.x - 1 - (int)blockIdx.x;  // heavy first
  const int q0 = tile * 128;
  const int h = blockIdx.y;
  const int t = threadIdx.x;
  const int lane = t & 63, w = t >> 6;
  const int g = lane >> 4, ln = lane & 15;

  // Q fragments (per-lane q-row = strip + ln), 2 strips of 16 rows per wave
  f16x8 qa[2][4];
  int klim[2];
  float m_run[2], l_run[2];
#pragma unroll
  for (int mi = 0; mi < 2; ++mi) {
    int qrow = min(q0 + w * 32 + mi * 16 + ln, L_SEQ - 1);
    klim[mi] = (qrow / FRAME + 1) * FRAME;
    m_run[mi] = -1e30f;
    l_run[mi] = 0.f;
    const f16* qb = &q16[(size_t)qrow * DIMSZ + h * HDIM + g * 8];
#pragma unroll
    for (int kc = 0; kc < 4; ++kc) qa[mi][kc] = *(const f16x8*)&qb[kc * 32];
  }
  f32x4 acc[2][8] = {};  // O^T: acc[mi][db][r] = O^T[d=db*16+4g+r][q=ln]

  const int rmax = min(q0 + 127, L_SEQ - 1);
  const int nkt = ((rmax / FRAME + 1) * FRAME + 63) >> 6;
  const size_t hbase = ((size_t)h * NKT_ALL) << 13;
#pragma unroll
  for (int i = 0; i < 4; ++i) {
    gll16(k16 + hbase + (i * 256 + t) * 8, &Ks[0][(i * 256 + t) * 8]);
    gll16(v16 + hbase + (i * 256 + t) * 8, &Vt[0][(i * 256 + t) * 8]);
  }

  int buf = 0;
  for (int kt = 0; kt < nkt; ++kt) {
    __syncthreads();
    if (kt + 1 < nkt) {
      size_t tb = hbase + ((size_t)(kt + 1) << 13);
      int b = buf ^ 1;
#pragma unroll
      for (int i = 0; i < 4; ++i) {
        gll16(k16 + tb + (i * 256 + t) * 8, &Ks[b][(i * 256 + t) * 8]);
        gll16(v16 + tb + (i * 256 + t) * 8, &Vt[b][(i * 256 + t) * 8]);
      }
    }
    const f16* Kb = Ks[buf];
    const f16* Vb = Vt[buf];

    // ---- S^T = K Q^T : D col=ln=q, row=4g+r=key (K frags shared across mi) ----
    f32x4 st[2][4] = {};
    __builtin_amdgcn_s_setprio(1);
#pragma unroll
    for (int nb = 0; nb < 4; ++nb) {
      int row = nb * 16 + ln;
#pragma unroll
      for (int kc = 0; kc < 4; ++kc) {
        f16x8 kb = *(const f16x8*)&Kb[row * 128 + ((g * 8 + kc * 32) ^ ((row & 7) * 8))];
        st[0][nb] = __builtin_amdgcn_mfma_f32_16x16x32_f16(kb, qa[0][kc], st[0][nb], 0, 0, 0);
        st[1][nb] = __builtin_amdgcn_mfma_f32_16x16x32_f16(kb, qa[1][kc], st[1][nb], 0, 0, 0);
      }
    }
    __builtin_amdgcn_s_setprio(0);

    // ---- per-lane online softmax (q = ln per lane), P stays in registers ----
    f16x4 pb[2][4];
#pragma unroll
    for (int mi = 0; mi < 2; ++mi) {
      float p[4][4];
      float rm = -1e30f;
#pragma unroll
      for (int nb = 0; nb < 4; ++nb)
#pragma unroll
        for (int r = 0; r < 4; ++r) {
          int key = kt * 64 + nb * 16 + 4 * g + r;
          float val = st[mi][nb][r];
          if (key >= klim[mi]) val = -1e30f;
          p[nb][r] = val;
          rm = fmaxf(rm, val);
        }
      rm = fmaxf(rm, __shfl_xor(rm, 16));
      rm = fmaxf(rm, __shfl_xor(rm, 32));
      float mn = fmaxf(m_run[mi], rm);
      float fs = exp2f(m_run[mi] - mn);
      m_run[mi] = mn;
      float sm = 0.f;
#pragma unroll
      for (int nb = 0; nb < 4; ++nb) {
        f16x4 pk;
#pragma unroll
        for (int r = 0; r < 4; ++r) {
          float e = exp2f(p[nb][r] - mn);
          sm += e;
          pk[r] = (f16)e;
        }
        pb[mi][nb] = pk;
      }
      sm += __shfl_xor(sm, 16);
      sm += __shfl_xor(sm, 32);
      l_run[mi] = l_run[mi] * fs + sm;
#pragma unroll
      for (int db = 0; db < 8; ++db)
#pragma unroll
        for (int r = 0; r < 4; ++r) acc[mi][db][r] *= fs;
    }

    // ---- O^T += V^T P^T : A = V^T (8B reads, shared across mi), B = P^T from regs ----
    __builtin_amdgcn_s_setprio(1);
#pragma unroll
    for (int db = 0; db < 8; ++db) {
      int d = db * 16 + ln;
#pragma unroll
      for (int nb = 0; nb < 4; ++nb) {
        f16x4 va = *(const f16x4*)&Vb[d * 64 + ((nb * 16 + 4 * g) ^ ((d & 7) * 8))];
        acc[0][db] = __builtin_amdgcn_mfma_f32_16x16x16f16(va, pb[0][nb], acc[0][db], 0, 0, 0);
        acc[1][db] = __builtin_amdgcn_mfma_f32_16x16x16f16(va, pb[1][nb], acc[1][db], 0, 0, 0);
      }
    }
    __builtin_amdgcn_s_setprio(0);
    buf ^= 1;
  }

  // ---- epilogue: per-wave LDS transpose -> coalesced stores ----
#pragma unroll
  for (int mi = 0; mi < 2; ++mi) {
    float rinv = 1.f / l_run[mi];
#pragma unroll
    for (int db = 0; db < 8; ++db) {
      f32x4 o;
#pragma unroll
      for (int r = 0; r < 4; ++r) o[r] = acc[mi][db][r] * rinv;
      *(f32x4*)&Os[w][ln][4 * g] = o;  // Os[q=ln][dloc=4g+r]
      asm volatile("s_waitcnt lgkmcnt(0)" ::: "memory");
#pragma unroll
      for (int r = 0; r < 4; ++r) {
        int q = q0 + w * 32 + mi * 16 + 4 * g + r;
        float val = Os[w][4 * g + r][ln];
        if (q < L_SEQ) ao[(size_t)q * DIMSZ + h * HDIM + db * 16 + ln] = val;
      }
      asm volatile("s_waitcnt lgkmcnt(0)" ::: "memory");
    }
  }
}

extern "C" void kernel_launch(void* const* d_in, const int* in_sizes, int n_in,
                              void* d_out, int out_size, void* d_ws, size_t ws_size,
                              hipStream_t stream) {
  const float* x  = (const float*)d_in[0];
  const float* wq = (const float*)d_in[1];
  const float* bq = (const float*)d_in[2];
  const float* wk = (const float*)d_in[3];
  const float* bk = (const float*)d_in[4];
  const float* wv = (const float*)d_in[5];
  const float* bv = (const float*)d_in[6];
  const float* wo = (const float*)d_in[7];
  const float* bo = (const float*)d_in[8];
  const float* gq = (const float*)d_in[9];
  const float* gk = (const float*)d_in[10];
  const float* freqs = (const float*)d_in[11];
  float* out = (float*)d_out;
  float* ws = (float*)d_ws;

  const size_t LD  = (size_t)L_SEQ * DIMSZ;          // 7,188,480
  const size_t XSZ = (size_t)37 * 48 * 4096;         // 7,274,496 (also = 12*74*8192)
  const size_t WSZ = (size_t)12 * 48 * 4096;         // 2,359,296

  float* qf = ws;
  float* kf = qf + LD;
  float* vf = kf + LD;
  u16* xs_hi = (u16*)(vf + LD);
  u16* xs_lo = xs_hi + XSZ;
  f16* v16   = (f16*)(xs_lo + XSZ);
  u16* wsp   = (u16*)((f16*)v16 + XSZ);
  u16 *wq_hi = wsp,            *wq_lo = wsp + WSZ;
  u16 *wk_hi = wsp + 2 * WSZ,  *wk_lo = wsp + 3 * WSZ;
  u16 *wv_hi = wsp + 4 * WSZ,  *wv_lo = wsp + 5 * WSZ;
  // overlays (sequential stream order makes these safe):
  f16* q16 = (f16*)xs_hi;       // after QKV GEMMs, xs dead
  f16* k16 = (f16*)xs_lo;
  float* ao = qf;               // after norm_rope, qf dead
  u16* aos_hi = (u16*)kf;       // after norm_rope/vconvert, kf/vf dead
  u16* aos_lo = (u16*)vf;
  u16* wo_hi = (u16*)xs_hi;     // after attn, q16 dead; wo split goes here
  u16* wo_lo = wo_hi + WSZ;     // fits: 2*WSZ < XSZ

  dim3 blk(256);
  split_bf16<<<dim3(37, 48), blk, 0, stream>>>(x, L_SEQ, xs_hi, xs_lo);
  split_bf16<<<dim3(12, 48), blk, 0, stream>>>(wq, DIMSZ, wq_hi, wq_lo);
  split_bf16<<<dim3(12, 48), blk, 0, stream>>>(wk, DIMSZ, wk_hi, wk_lo);
  split_bf16<<<dim3(12, 48), blk, 0, stream>>>(wv, DIMSZ, wv_hi, wv_lo);
  gemm_split<<<dim3(37, 12), blk, 0, stream>>>(xs_hi, xs_lo, wq_hi, wq_lo, bq, qf, L_SEQ);
  gemm_split<<<dim3(37, 12), blk, 0, stream>>>(xs_hi, xs_lo, wk_hi, wk_lo, bk, kf, L_SEQ);
  gemm_split<<<dim3(37, 12), blk, 0, stream>>>(xs_hi, xs_lo, wv_hi, wv_lo, bv, vf, L_SEQ);
  norm_rope<<<dim3(L_SEQ, 2), blk, 0, stream>>>(qf, kf, gq, gk, freqs, q16, k16);
  vconvert<<<dim3(NKT_ALL, NHEAD), blk, 0, stream>>>(vf, v16);
  attn_mfma<<<dim3(37, NHEAD), blk, 0, stream>>>(q16, k16, v16, ao);
  split_bf16<<<dim3(37, 48), blk, 0, stream>>>(ao, L_SEQ, aos_hi, aos_lo);
  split_bf16<<<dim3(12, 48), blk, 0, stream>>>(wo, DIMSZ, wo_hi, wo_lo);
  gemm_split<<<dim3(37, 12), blk, 0, stream>>>(aos_hi, aos_lo, wo_hi, wo_lo, bo, out, L_SEQ);
}